// Round 1
// baseline (151.558 us; speedup 1.0000x reference)
//
#include <hip/hip_runtime.h>
#include <hip/hip_bf16.h>
#include <stdint.h>

// Problem constants
#define BB    32
#define CIN   1024
#define TT    7
#define HHWW  196      // 14*14
#define HW4   49       // 196/4
#define CI    512      // C_INTER
#define TMID  3
#define MM    (BB*HHWW)   // 6272 = 49*128

using bf16 = __hip_bfloat16;
typedef __attribute__((ext_vector_type(8))) short short8;
typedef __attribute__((ext_vector_type(4))) float f32x4;

// ---------------------------------------------------------------- prep ----
// key[t][d] = sum_c nodes[t][c]*Wk[c][d] + bk[d]
__global__ void k_key(const float* __restrict__ nodes, const float* __restrict__ Wk,
                      const float* __restrict__ bk, float* __restrict__ key) {
    int t = blockIdx.x, d = threadIdx.x;
    float acc = bk[d];
    const float* nr = nodes + t * CI;
    for (int c = 0; c < CI; ++c) acc = fmaf(nr[c], Wk[(size_t)c * CI + d], acc);
    key[t * CI + d] = acc;
}

// Wqk[c][t] = sum_d Wq[c][d]*key[t][d]   (c==CIN row computes bqk from bq)
__global__ void k_wqk(const float* __restrict__ Wq, const float* __restrict__ bq,
                      const float* __restrict__ key, float* __restrict__ Wqk,
                      float* __restrict__ bqk) {
    int c = blockIdx.x;          // 0..1024 (1024 == bqk row)
    int lane = threadIdx.x;      // 64 threads = 1 wave
    float acc[TT] = {0,0,0,0,0,0,0};
    const float* src = (c < CIN) ? (Wq + (size_t)c * CI) : bq;
    for (int it = 0; it < CI / 64; ++it) {
        float w = src[it * 64 + lane];
        #pragma unroll
        for (int t = 0; t < TT; ++t) acc[t] += w * key[t * CI + it * 64 + lane];
    }
    #pragma unroll
    for (int t = 0; t < TT; ++t) {
        float v = acc[t];
        for (int off = 32; off; off >>= 1) v += __shfl_down(v, off);
        if (lane == 0) { if (c < CIN) Wqk[c * 8 + t] = v; else bqk[t] = v; }
    }
}

// Wv -> bf16 (same layout [c][d]); Wo[d][c'] -> WoT_bf[c'][d]
__global__ __launch_bounds__(256) void k_convw(const float* __restrict__ Wv,
                                               const float* __restrict__ Wo,
                                               bf16* __restrict__ Wv_bf,
                                               bf16* __restrict__ WoT_bf) {
    int i = blockIdx.x * 256 + threadIdx.x;  // < 524288
    Wv_bf[i] = __float2bfloat16(Wv[i]);
    int d = i >> 10, cp = i & 1023;
    WoT_bf[(size_t)cp * CI + d] = __float2bfloat16(Wo[i]);
}

// bvo[c'] = bo[c'] + sum_d bv[d]*Wo[d][c']
__global__ void k_bvo(const float* __restrict__ Wo, const float* __restrict__ bv,
                      const float* __restrict__ bo, float* __restrict__ bvo) {
    int cp = blockIdx.x * 256 + threadIdx.x;  // < 1024
    float acc = bo[cp];
    for (int d = 0; d < CI; ++d) acc = fmaf(bv[d], Wo[(size_t)d * CIN + cp], acc);
    bvo[cp] = acc;
}

// ---------------------------------------------------------------- alpha ----
// partial logits: part[b][chunk][t][hw] = sum_{c in chunk} x[b][c][3][hw]*Wqk[c][t]
__global__ __launch_bounds__(256) void k_alpha(const float* __restrict__ x,
                                               const float* __restrict__ Wqk,
                                               float* __restrict__ part) {
    int chunk = blockIdx.x;  // 8
    int b = blockIdx.y;      // 32
    int tid = threadIdx.x;
    __shared__ float wq_s[128 * 8];
    for (int i = tid; i < 1024; i += 256) wq_s[i] = Wqk[chunk * 1024 + i];
    __syncthreads();
    if (tid < HHWW) {
        float acc[TT] = {0,0,0,0,0,0,0};
        const float* xb = x + (size_t)(b * CIN + chunk * 128) * TT * HHWW + TMID * HHWW + tid;
        #pragma unroll 4
        for (int c = 0; c < 128; ++c) {
            float v = xb[(size_t)c * TT * HHWW];
            #pragma unroll
            for (int t = 0; t < TT; ++t) acc[t] += v * wq_s[c * 8 + t];
        }
        #pragma unroll
        for (int t = 0; t < TT; ++t)
            part[((size_t)(b * 8 + chunk) * TT + t) * HHWW + tid] = acc[t];
    }
}

// reduce partials + softmax over t
__global__ void k_softmax(const float* __restrict__ part, const float* __restrict__ bqk,
                          float* __restrict__ alpha) {
    int i = blockIdx.x * 256 + threadIdx.x;
    if (i >= MM) return;
    int b = i / HHWW, j = i - b * HHWW;
    float s[TT];
    #pragma unroll
    for (int t = 0; t < TT; ++t) s[t] = bqk[t];
    for (int ch = 0; ch < 8; ++ch)
        #pragma unroll
        for (int t = 0; t < TT; ++t) s[t] += part[((size_t)(b * 8 + ch) * TT + t) * HHWW + j];
    float mx = s[0];
    #pragma unroll
    for (int t = 1; t < TT; ++t) mx = fmaxf(mx, s[t]);
    float e[TT], sum = 0.f;
    #pragma unroll
    for (int t = 0; t < TT; ++t) { e[t] = expf(s[t] - mx); sum += e[t]; }
    float inv = 1.f / sum;
    #pragma unroll
    for (int t = 0; t < TT; ++t) alpha[((size_t)b * TT + t) * HHWW + j] = e[t] * inv;
}

// ---------------------------------------------------------------- xw ----
// xw[m=(b,hw)][c] = bf16( sum_t alpha[b][t][hw] * x[b][c][t][hw] )
__global__ __launch_bounds__(256) void k_xw(const float* __restrict__ x,
                                            const float* __restrict__ alpha,
                                            bf16* __restrict__ xw) {
    int i = blockIdx.x * 256 + threadIdx.x;  // < 32*1024*49
    int hw4 = i % HW4;
    int tmp = i / HW4;
    int c = tmp & (CIN - 1);
    int b = tmp >> 10;
    const f32x4* xp = (const f32x4*)x;
    const f32x4* ap = (const f32x4*)alpha;
    f32x4 acc = {0.f, 0.f, 0.f, 0.f};
    size_t xbase = (size_t)(b * CIN + c) * TT * HW4 + hw4;
    size_t abase = (size_t)b * TT * HW4 + hw4;
    #pragma unroll
    for (int t = 0; t < TT; ++t) {
        f32x4 al = ap[abase + (size_t)t * HW4];
        f32x4 xv = xp[xbase + (size_t)t * HW4];
        acc += al * xv;
    }
    int m0 = b * HHWW + hw4 * 4;
    size_t o = (size_t)m0 * CIN + c;
    xw[o]           = __float2bfloat16(acc[0]);
    xw[o + CIN]     = __float2bfloat16(acc[1]);
    xw[o + 2 * CIN] = __float2bfloat16(acc[2]);
    xw[o + 3 * CIN] = __float2bfloat16(acc[3]);
}

// ---------------------------------------------------------------- GEMM ----
__device__ __forceinline__ void gload_lds16(const void* g, void* l) {
    __builtin_amdgcn_global_load_lds((const __attribute__((address_space(1))) void*)g,
                                     (__attribute__((address_space(3))) void*)l, 16, 0, 0);
}

// TN GEMM: A[m][k] (K-contig), Bt[n][k] (K-contig), bf16 in, f32 accum.
// EPI 0: bf16 C[m][n].  EPI 1: f32 out[b][n][hw] (m=(b,hw)) + bias[n].
template <int EPI>
__global__ __launch_bounds__(256) void k_gemm(const bf16* __restrict__ A,
                                              const bf16* __restrict__ Bt,
                                              void* __restrict__ Cout,
                                              const float* __restrict__ bias,
                                              int M, int N, int K) {
    __shared__ __align__(16) bf16 As[128 * 64];
    __shared__ __align__(16) bf16 Bs[128 * 64];
    int bm = blockIdx.x, bn = blockIdx.y;
    int tid = threadIdx.x;
    int wid = tid >> 6, lane = tid & 63;
    int wr = wid >> 1, wc = wid & 1;   // 2x2 waves, each 64x64
    f32x4 acc[4][4] = {};
    const bf16* Ab = A + (size_t)bm * 128 * K;
    const bf16* Bb = Bt + (size_t)bn * 128 * K;
    int row = lane & 15;
    int kb_base = (lane >> 4) * 8;

    for (int k0 = 0; k0 < K; k0 += 64) {
        #pragma unroll
        for (int it = 0; it < 4; ++it) {
            int e = (it * 256 + tid) * 8;   // bf16 elem index in 128x64 tile
            int r = e >> 6, cc = e & 63;
            gload_lds16(Ab + (size_t)r * K + k0 + cc, &As[e]);
            gload_lds16(Bb + (size_t)r * K + k0 + cc, &Bs[e]);
        }
        __syncthreads();
        #pragma unroll
        for (int kk = 0; kk < 2; ++kk) {
            int kb = kk * 32 + kb_base;
            short8 a[4], b[4];
            #pragma unroll
            for (int mi = 0; mi < 4; ++mi) a[mi] = *(const short8*)&As[(wr * 64 + mi * 16 + row) * 64 + kb];
            #pragma unroll
            for (int ni = 0; ni < 4; ++ni) b[ni] = *(const short8*)&Bs[(wc * 64 + ni * 16 + row) * 64 + kb];
            #pragma unroll
            for (int mi = 0; mi < 4; ++mi)
                #pragma unroll
                for (int ni = 0; ni < 4; ++ni)
                    acc[mi][ni] = __builtin_amdgcn_mfma_f32_16x16x32_bf16(a[mi], b[ni], acc[mi][ni], 0, 0, 0);
        }
        __syncthreads();
    }

    int col_l = lane & 15, row_l = (lane >> 4) * 4;
    if constexpr (EPI == 0) {
        bf16* C = (bf16*)Cout;
        #pragma unroll
        for (int mi = 0; mi < 4; ++mi) {
            int row0 = bm * 128 + wr * 64 + mi * 16 + row_l;
            #pragma unroll
            for (int ni = 0; ni < 4; ++ni) {
                int col = bn * 128 + wc * 64 + ni * 16 + col_l;
                #pragma unroll
                for (int r = 0; r < 4; ++r)
                    C[(size_t)(row0 + r) * N + col] = __float2bfloat16(acc[mi][ni][r]);
            }
        }
    } else {
        float* Cf = (float*)Cout;
        #pragma unroll
        for (int ni = 0; ni < 4; ++ni) {
            int n = bn * 128 + wc * 64 + ni * 16 + col_l;
            float bz = bias[n];
            #pragma unroll
            for (int mi = 0; mi < 4; ++mi) {
                int m0 = bm * 128 + wr * 64 + mi * 16 + row_l;  // 4-aligned
                int b = m0 / HHWW;
                int hw0 = m0 - b * HHWW;                         // hw0%4==0, hw0+3<196
                f32x4 v = acc[mi][ni];
                v[0] += bz; v[1] += bz; v[2] += bz; v[3] += bz;
                *(f32x4*)&Cf[((size_t)b * CIN + n) * HHWW + hw0] = v;
            }
        }
    }
}

// ---------------------------------------------------------------- launch ----
extern "C" void kernel_launch(void* const* d_in, const int* in_sizes, int n_in,
                              void* d_out, int out_size, void* d_ws, size_t ws_size,
                              hipStream_t stream) {
    const float* x     = (const float*)d_in[0];
    const float* nodes = (const float*)d_in[1];
    const float* Wq    = (const float*)d_in[2];
    const float* bq    = (const float*)d_in[3];
    const float* Wk    = (const float*)d_in[4];
    const float* bk    = (const float*)d_in[5];
    const float* Wv    = (const float*)d_in[6];
    const float* bv    = (const float*)d_in[7];
    const float* Wo    = (const float*)d_in[8];
    const float* bo    = (const float*)d_in[9];

    uint8_t* w = (uint8_t*)d_ws;
    size_t off = 0;
    auto alloc = [&](size_t bytes) -> void* {
        void* p = w + off;
        off = (off + bytes + 255) & ~(size_t)255;
        return p;
    };
    float* key    = (float*)alloc((size_t)TT * CI * 4);
    float* Wqk    = (float*)alloc((size_t)CIN * 8 * 4);
    float* bqk    = (float*)alloc(8 * 4);
    float* bvo    = (float*)alloc((size_t)CIN * 4);
    bf16*  Wv_bf  = (bf16*)alloc((size_t)CIN * CI * 2);
    bf16*  WoT_bf = (bf16*)alloc((size_t)CIN * CI * 2);
    bf16*  WvoT   = (bf16*)alloc((size_t)CIN * CIN * 2);
    float* part   = (float*)alloc((size_t)BB * 8 * TT * HHWW * 4);
    float* alpha  = (float*)alloc((size_t)BB * TT * HHWW * 4);
    bf16*  xw     = (bf16*)alloc((size_t)MM * CIN * 2);
    (void)ws_size;  // needs ~18.7 MB

    k_key<<<TT, CI, 0, stream>>>(nodes, Wk, bk, key);
    k_wqk<<<CIN + 1, 64, 0, stream>>>(Wq, bq, key, Wqk, bqk);
    k_convw<<<2048, 256, 0, stream>>>(Wv, Wo, Wv_bf, WoT_bf);
    k_bvo<<<4, 256, 0, stream>>>(Wo, bv, bo, bvo);
    // WvoT[c'][c] = sum_d WoT[c'][d] * Wv[c][d]   (M=1024,N=1024,K=512)
    k_gemm<0><<<dim3(8, 8), 256, 0, stream>>>(WoT_bf, Wv_bf, (void*)WvoT, nullptr, 1024, 1024, 512);
    k_alpha<<<dim3(8, BB), 256, 0, stream>>>(x, Wqk, part);
    k_softmax<<<(MM + 255) / 256, 256, 0, stream>>>(part, bqk, alpha);
    k_xw<<<(BB * CIN * HW4) / 256, 256, 0, stream>>>(x, alpha, xw);
    // out[b][c'][hw] = sum_c xw[m][c] * WvoT[c'][c] + bvo[c']   (M=6272,N=1024,K=1024)
    k_gemm<1><<<dim3(MM / 128, CIN / 128), 256, 0, stream>>>(xw, WvoT, d_out, bvo, MM, 1024, 1024);
}

// Round 2
// 100.531 us; speedup vs baseline: 1.5076x; 1.5076x over previous
//
#include <hip/hip_runtime.h>
#include <hip/hip_bf16.h>
#include <stdint.h>

// Problem constants
#define BB    32
#define CIN   1024
#define TT    7
#define HHWW  196      // 14*14
#define HW4   49       // 196/4
#define CI    512      // C_INTER
#define TMID  3
#define MM    (BB*HHWW)   // 6272 = 49*128

using bf16 = __hip_bfloat16;
typedef __attribute__((ext_vector_type(8))) short short8;
typedef __attribute__((ext_vector_type(4))) short s16x4;
typedef __attribute__((ext_vector_type(4))) float f32x4;

__device__ __forceinline__ void gload_lds16(const void* g, void* l) {
    __builtin_amdgcn_global_load_lds((const __attribute__((address_space(1))) void*)g,
                                     (__attribute__((address_space(3))) void*)l, 16, 0, 0);
}

// ---------------------------------------------------------------- GEMM body ----
// TN GEMM: A[m][k] (K-contig), Bt[n][k] (K-contig), bf16 in, f32 accum.
// EPI 0: bf16 C[m][n].  EPI 1: f32 out[b][n][hw] (m=(b,hw)) + bias[n].
template <int EPI>
__device__ __forceinline__ void gemm_body(const bf16* __restrict__ A, const bf16* __restrict__ Bt,
                                          void* __restrict__ Cout, const float* __restrict__ bias,
                                          int M, int N, int K, int bm, int bn,
                                          bf16 (&As)[128 * 64], bf16 (&Bs)[128 * 64]) {
    int tid = threadIdx.x;
    int wid = tid >> 6, lane = tid & 63;
    int wr = wid >> 1, wc = wid & 1;   // 2x2 waves, each 64x64
    f32x4 acc[4][4] = {};
    const bf16* Ab = A + (size_t)bm * 128 * K;
    const bf16* Bb = Bt + (size_t)bn * 128 * K;
    int row = lane & 15;
    int kb_base = (lane >> 4) * 8;

    for (int k0 = 0; k0 < K; k0 += 64) {
        #pragma unroll
        for (int it = 0; it < 4; ++it) {
            int e = (it * 256 + tid) * 8;   // bf16 elem index in 128x64 tile
            int r = e >> 6, cc = e & 63;
            gload_lds16(Ab + (size_t)r * K + k0 + cc, &As[e]);
            gload_lds16(Bb + (size_t)r * K + k0 + cc, &Bs[e]);
        }
        __syncthreads();
        #pragma unroll
        for (int kk = 0; kk < 2; ++kk) {
            int kb = kk * 32 + kb_base;
            short8 a[4], b[4];
            #pragma unroll
            for (int mi = 0; mi < 4; ++mi) a[mi] = *(const short8*)&As[(wr * 64 + mi * 16 + row) * 64 + kb];
            #pragma unroll
            for (int ni = 0; ni < 4; ++ni) b[ni] = *(const short8*)&Bs[(wc * 64 + ni * 16 + row) * 64 + kb];
            #pragma unroll
            for (int mi = 0; mi < 4; ++mi)
                #pragma unroll
                for (int ni = 0; ni < 4; ++ni)
                    acc[mi][ni] = __builtin_amdgcn_mfma_f32_16x16x32_bf16(a[mi], b[ni], acc[mi][ni], 0, 0, 0);
        }
        __syncthreads();
    }

    int col_l = lane & 15, row_l = (lane >> 4) * 4;
    if constexpr (EPI == 0) {
        bf16* C = (bf16*)Cout;
        #pragma unroll
        for (int mi = 0; mi < 4; ++mi) {
            int row0 = bm * 128 + wr * 64 + mi * 16 + row_l;
            #pragma unroll
            for (int ni = 0; ni < 4; ++ni) {
                int col = bn * 128 + wc * 64 + ni * 16 + col_l;
                #pragma unroll
                for (int r = 0; r < 4; ++r)
                    C[(size_t)(row0 + r) * N + col] = __float2bfloat16(acc[mi][ni][r]);
            }
        }
    } else {
        float* Cf = (float*)Cout;
        #pragma unroll
        for (int ni = 0; ni < 4; ++ni) {
            int n = bn * 128 + wc * 64 + ni * 16 + col_l;
            float bz = bias[n];
            #pragma unroll
            for (int mi = 0; mi < 4; ++mi) {
                int m0 = bm * 128 + wr * 64 + mi * 16 + row_l;  // 4-aligned
                int b = m0 / HHWW;
                int hw0 = m0 - b * HHWW;                         // hw0%4==0, hw0+3<196
                f32x4 v = acc[mi][ni];
                v[0] += bz; v[1] += bz; v[2] += bz; v[3] += bz;
                *(f32x4*)&Cf[((size_t)b * CIN + n) * HHWW + hw0] = v;
            }
        }
    }
}

// ---------------------------------------------------------------- K1: key | convw | bvo ----
__global__ __launch_bounds__(256) void k_prep1(
    const float* __restrict__ nodes, const float* __restrict__ Wk, const float* __restrict__ bk,
    float* __restrict__ key,
    const float* __restrict__ Wv, const float* __restrict__ Wo,
    bf16* __restrict__ Wv_bf, bf16* __restrict__ WoT_bf,
    const float* __restrict__ bv, const float* __restrict__ bo, float* __restrict__ bvo) {
    __shared__ float sred[512];
    int bid = blockIdx.x, tid = threadIdx.x;
    if (bid < 56) {
        // key[t][d] = sum_c nodes[t][c]*Wk[c][d] + bk[d]; block=(t,dchunk of 64)
        int t = bid >> 3, dc = bid & 7;
        int d_l = tid & 63, q = tid >> 6;
        int d = dc * 64 + d_l;
        float acc = 0.f;
        const float* nr = nodes + t * CI;
        #pragma unroll 4
        for (int c = q * 128; c < q * 128 + 128; ++c)
            acc = fmaf(nr[c], Wk[(size_t)c * CI + d], acc);
        sred[q * 64 + d_l] = acc;
        __syncthreads();
        if (q == 0)
            key[t * CI + d] = sred[d_l] + sred[64 + d_l] + sred[128 + d_l] + sred[192 + d_l] + bk[d];
    } else if (bid < 56 + 2048) {
        // Wv -> bf16; Wo[d][c'] -> WoT_bf[c'][d]
        int i = (bid - 56) * 256 + tid;
        Wv_bf[i] = __float2bfloat16(Wv[i]);
        int d = i >> 10, cp = i & 1023;
        WoT_bf[(size_t)cp * CI + d] = __float2bfloat16(Wo[i]);
    } else {
        // bvo[c'] = bo[c'] + sum_d bv[d]*Wo[d][c']; block = 32 cp, 8 d-groups
        int cp0 = (bid - 2104) * 32;
        int cp_l = tid & 31, dq = tid >> 5;
        float acc = 0.f;
        #pragma unroll 4
        for (int d = dq * 64; d < dq * 64 + 64; ++d)
            acc = fmaf(bv[d], Wo[(size_t)d * CIN + cp0 + cp_l], acc);
        sred[dq * 32 + cp_l] = acc;
        __syncthreads();
        if (dq == 0) {
            float v = bo[cp0 + cp_l];
            #pragma unroll
            for (int g = 0; g < 8; ++g) v += sred[g * 32 + cp_l];
            bvo[cp0 + cp_l] = v;
        }
    }
}

// ---------------------------------------------------------------- K2: Wqk ----
// Wqk[c][t] = sum_d Wq[c][d]*key[t][d]; c==CIN row computes bqk from bq. 4 waves/block.
__global__ __launch_bounds__(256) void k_wqk(const float* __restrict__ Wq, const float* __restrict__ bq,
                                             const float* __restrict__ key, float* __restrict__ Wqk,
                                             float* __restrict__ bqk) {
    int c = blockIdx.x * 4 + (threadIdx.x >> 6);
    int lane = threadIdx.x & 63;
    if (c > CIN) return;
    const float* src = (c < CIN) ? (Wq + (size_t)c * CI) : bq;
    float acc[TT] = {};
    #pragma unroll 2
    for (int it = 0; it < CI / 64; ++it) {
        float w = src[it * 64 + lane];
        #pragma unroll
        for (int t = 0; t < TT; ++t) acc[t] = fmaf(w, key[t * CI + it * 64 + lane], acc[t]);
    }
    #pragma unroll
    for (int t = 0; t < TT; ++t) {
        float v = acc[t];
        for (int off = 32; off; off >>= 1) v += __shfl_down(v, off);
        if (lane == 0) { if (c < CIN) Wqk[c * 8 + t] = v; else bqk[t] = v; }
    }
}

// ---------------------------------------------------------------- K3: alpha | gemm0 ----
// alpha role: part[b][chunk][t][hw] = sum_{c in chunk128} x[b][c][3][hw]*Wqk[c][t]
// gemm0 role: WvoT[c'][c] = sum_d WoT[c'][d]*Wv[c][d]  (1024x1024, K=512)
__global__ __launch_bounds__(256) void k_prep3(
    const float* __restrict__ x, const float* __restrict__ Wqk, float* __restrict__ part,
    const bf16* __restrict__ WoT_bf, const bf16* __restrict__ Wv_bf, bf16* __restrict__ WvoT) {
    __shared__ __align__(16) bf16 As[128 * 64];
    __shared__ __align__(16) bf16 Bs[128 * 64];
    __shared__ float wq_s[128 * 8];
    int bid = blockIdx.x, tid = threadIdx.x;
    if (bid < 64) {
        gemm_body<0>(WoT_bf, Wv_bf, (void*)WvoT, nullptr, 1024, 1024, 512, bid >> 3, bid & 7, As, Bs);
        return;
    }
    int ab = bid - 64;
    int chunk = ab & 7, b = ab >> 3;
    for (int i = tid; i < 1024; i += 256) wq_s[i] = Wqk[chunk * 1024 + i];
    __syncthreads();
    if (tid < HHWW) {
        float acc[TT] = {};
        const float* xb = x + (size_t)(b * CIN + chunk * 128) * TT * HHWW + TMID * HHWW + tid;
        #pragma unroll 4
        for (int c = 0; c < 128; ++c) {
            float v = xb[(size_t)c * TT * HHWW];
            #pragma unroll
            for (int t = 0; t < TT; ++t) acc[t] = fmaf(v, wq_s[c * 8 + t], acc[t]);
        }
        #pragma unroll
        for (int t = 0; t < TT; ++t)
            part[((size_t)(b * 8 + chunk) * TT + t) * HHWW + tid] = acc[t];
    }
}

// ---------------------------------------------------------------- K4: softmax + xw ----
// Block (c0=32-chunk, b). Phase A: softmax from part -> al[] in LDS.
// Phase B: acc[m4][c] = sum_t al*x, into LDS transpose buffer (XOR swizzle).
// Phase C: coalesced bf16x4 writes of xw[m][c].
__global__ __launch_bounds__(256) void k_smxw(const float* __restrict__ x,
                                              const float* __restrict__ part,
                                              const float* __restrict__ bqk,
                                              bf16* __restrict__ xw) {
    __shared__ __align__(16) float al[TT * HHWW];   // 5488 B
    __shared__ __align__(16) bf16 txp[HHWW * 32];   // 12544 B
    int c0 = blockIdx.x * 32;
    int b = blockIdx.y;
    int tid = threadIdx.x;
    // ---- phase A: softmax over t for each hw
    if (tid < HHWW) {
        float s[TT];
        #pragma unroll
        for (int t = 0; t < TT; ++t) s[t] = bqk[t];
        #pragma unroll
        for (int ch = 0; ch < 8; ++ch)
            #pragma unroll
            for (int t = 0; t < TT; ++t)
                s[t] += part[((size_t)(b * 8 + ch) * TT + t) * HHWW + tid];
        float mx = s[0];
        #pragma unroll
        for (int t = 1; t < TT; ++t) mx = fmaxf(mx, s[t]);
        float e[TT], sum = 0.f;
        #pragma unroll
        for (int t = 0; t < TT; ++t) { e[t] = __expf(s[t] - mx); sum += e[t]; }
        float inv = 1.f / sum;
        #pragma unroll
        for (int t = 0; t < TT; ++t) al[t * HHWW + tid] = e[t] * inv;
    }
    __syncthreads();
    // ---- phase B: weighted t-sum; items = 32c x 49hw4
    const f32x4* xp = (const f32x4*)x;
    f32x4 acc[7] = {};
    #pragma unroll
    for (int t = 0; t < TT; ++t) {
        #pragma unroll
        for (int k = 0; k < 7; ++k) {
            int w = k * 256 + tid;
            if (k == 6 && w >= 1568) continue;
            int c_l = w / 49;
            int hw4 = w - c_l * 49;
            f32x4 a4 = *(const f32x4*)&al[t * HHWW + hw4 * 4];
            f32x4 xv = xp[((size_t)(b * CIN + c0 + c_l) * TT + t) * HW4 + hw4];
            acc[k] += a4 * xv;
        }
    }
    #pragma unroll
    for (int k = 0; k < 7; ++k) {
        int w = k * 256 + tid;
        if (k == 6 && w >= 1568) continue;
        int c_l = w / 49;
        int hw4 = w - c_l * 49;
        int v = (hw4 & 7) << 2;
        #pragma unroll
        for (int r = 0; r < 4; ++r)
            txp[(hw4 * 4 + r) * 32 + (c_l ^ v)] = __float2bfloat16(acc[k][r]);
    }
    __syncthreads();
    // ---- phase C: coalesced write-out; items = 196m x 8 segs
    #pragma unroll
    for (int k = 0; k < 7; ++k) {
        int w = k * 256 + tid;
        if (k == 6 && w >= 1568) continue;
        int m = w >> 3, seg = w & 7;
        int v = ((m >> 2) & 7) << 2;
        s16x4 val = *(const s16x4*)&txp[m * 32 + ((seg * 4) ^ v)];
        *(s16x4*)&xw[(size_t)(b * HHWW + m) * CIN + c0 + seg * 4] = val;
    }
}

// ---------------------------------------------------------------- K5: main GEMM ----
__global__ __launch_bounds__(256) void k_gemm1(const bf16* __restrict__ A, const bf16* __restrict__ Bt,
                                               float* __restrict__ C, const float* __restrict__ bias) {
    __shared__ __align__(16) bf16 As[128 * 64];
    __shared__ __align__(16) bf16 Bs[128 * 64];
    gemm_body<1>(A, Bt, (void*)C, bias, MM, CIN, CIN, blockIdx.x, blockIdx.y, As, Bs);
}

// ---------------------------------------------------------------- launch ----
extern "C" void kernel_launch(void* const* d_in, const int* in_sizes, int n_in,
                              void* d_out, int out_size, void* d_ws, size_t ws_size,
                              hipStream_t stream) {
    const float* x     = (const float*)d_in[0];
    const float* nodes = (const float*)d_in[1];
    const float* Wq    = (const float*)d_in[2];
    const float* bq    = (const float*)d_in[3];
    const float* Wk    = (const float*)d_in[4];
    const float* bk    = (const float*)d_in[5];
    const float* Wv    = (const float*)d_in[6];
    const float* bv    = (const float*)d_in[7];
    const float* Wo    = (const float*)d_in[8];
    const float* bo    = (const float*)d_in[9];

    uint8_t* w = (uint8_t*)d_ws;
    size_t off = 0;
    auto alloc = [&](size_t bytes) -> void* {
        void* p = w + off;
        off = (off + bytes + 255) & ~(size_t)255;
        return p;
    };
    float* key    = (float*)alloc((size_t)TT * CI * 4);
    float* Wqk    = (float*)alloc((size_t)CIN * 8 * 4);
    float* bqk    = (float*)alloc(8 * 4);
    float* bvo    = (float*)alloc((size_t)CIN * 4);
    bf16*  Wv_bf  = (bf16*)alloc((size_t)CIN * CI * 2);
    bf16*  WoT_bf = (bf16*)alloc((size_t)CIN * CI * 2);
    bf16*  WvoT   = (bf16*)alloc((size_t)CIN * CIN * 2);
    float* part   = (float*)alloc((size_t)BB * 8 * TT * HHWW * 4);
    bf16*  xw     = (bf16*)alloc((size_t)MM * CIN * 2);
    (void)ws_size;  // ~18 MB

    k_prep1<<<2136, 256, 0, stream>>>(nodes, Wk, bk, key, Wv, Wo, Wv_bf, WoT_bf, bv, bo, bvo);
    k_wqk<<<257, 256, 0, stream>>>(Wq, bq, key, Wqk, bqk);
    k_prep3<<<320, 256, 0, stream>>>(x, Wqk, part, WoT_bf, Wv_bf, WvoT);
    k_smxw<<<dim3(32, BB), 256, 0, stream>>>(x, part, bqk, xw);
    k_gemm1<<<dim3(MM / 128, CIN / 128), 256, 0, stream>>>(xw, WvoT, (float*)d_out, bvo);
}